// Round 6
// baseline (174.418 us; speedup 1.0000x reference)
//
#include <hip/hip_runtime.h>

// Problem constants (fixed by reference)
#define N_NODES 2048
#define EMBED   32
#define B_BATCH 16
#define INP     32
#define OUTC    32
#define NCOL    512
#define CHEB_K  3

// R5: k_final restructured as split-d (32 blocks, one per embed dim d):
// W read once chip-wide, Mp reduced with coalesced row reads, atomicAdd into
// zeroed d_out. k_inv widened 8->64 blocks. (R4's k_final: 16 blocks each
// re-reading all 384KB of W -> 6MB latency-bound fetch, 51us.)

// ---------------------------------------------------------------------------
// k_gram: 64x64 tiles. Ehat[i][j] = exp(exp(-gamma*dist(i,j))) * drop[i][j],
// Psum[jt][i] = sum_{j in tile jt} exp(exp(-gamma*dist)).  grid (32 jt, 32 it).
// ---------------------------------------------------------------------------
__global__ __launch_bounds__(256) void k_gram(
    const float* __restrict__ adj, const float* __restrict__ gammap,
    const float* __restrict__ drop,
    float* __restrict__ Ehat, float* __restrict__ Psum)
{
    __shared__ float ai[64][36];     // [row][k], float4 along k
    __shared__ float ajT[32][68];    // [k][col], float4 along col
    __shared__ float nI[64], nJ[64];
    __shared__ float rm[64][17];
    const int tid = threadIdx.x;
    const int j0 = blockIdx.x * 64;
    const int i0 = blockIdx.y * 64;
    const float gamma = gammap[0];

#pragma unroll
    for (int r = 0; r < 8; r++) {
        const int idx = r * 256 + tid;           // 0..2047
        ai[idx >> 5][idx & 31]  = adj[(size_t)(i0 + (idx >> 5)) * EMBED + (idx & 31)];
        ajT[idx & 31][idx >> 5] = adj[(size_t)(j0 + (idx >> 5)) * EMBED + (idx & 31)];
    }
    __syncthreads();
    if (tid < 64) {
        float s = 0.f;
#pragma unroll
        for (int k = 0; k < 32; k++) { const float v = ai[tid][k]; s += v * v; }
        nI[tid] = s;
    } else if (tid < 128) {
        const int col = tid - 64;
        float s = 0.f;
#pragma unroll
        for (int k = 0; k < 32; k++) { const float v = ajT[k][col]; s += v * v; }
        nJ[col] = s;
    }
    __syncthreads();

    const int ti = tid >> 4;        // rows ti*4..+3
    const int tj = tid & 15;        // cols tj*4..+3
    float acc[4][4] = {};
#pragma unroll
    for (int k4 = 0; k4 < 8; k4++) {
        float4 a4[4], b4[4];
#pragma unroll
        for (int r = 0; r < 4; r++) a4[r] = *(const float4*)&ai[ti * 4 + r][k4 * 4];
#pragma unroll
        for (int kk = 0; kk < 4; kk++) b4[kk] = *(const float4*)&ajT[k4 * 4 + kk][tj * 4];
#pragma unroll
        for (int r = 0; r < 4; r++) {
            acc[r][0] += a4[r].x * b4[0].x + a4[r].y * b4[1].x + a4[r].z * b4[2].x + a4[r].w * b4[3].x;
            acc[r][1] += a4[r].x * b4[0].y + a4[r].y * b4[1].y + a4[r].z * b4[2].y + a4[r].w * b4[3].y;
            acc[r][2] += a4[r].x * b4[0].z + a4[r].y * b4[1].z + a4[r].z * b4[2].z + a4[r].w * b4[3].z;
            acc[r][3] += a4[r].x * b4[0].w + a4[r].y * b4[1].w + a4[r].z * b4[2].w + a4[r].w * b4[3].w;
        }
    }
#pragma unroll
    for (int r = 0; r < 4; r++) {
        const int i = i0 + ti * 4 + r;
        const float ni = nI[ti * 4 + r];
        float e[4];
#pragma unroll
        for (int c = 0; c < 4; c++) {
            const float dist = ni + nJ[tj * 4 + c] - 2.f * acc[r][c];
            e[c] = __expf(__expf(-gamma * dist));
        }
        rm[ti * 4 + r][tj] = e[0] + e[1] + e[2] + e[3];
        const float4 dr = *(const float4*)&drop[(size_t)i * N_NODES + j0 + tj * 4];
        *(float4*)(&Ehat[(size_t)i * N_NODES + j0 + tj * 4]) =
            make_float4(e[0] * dr.x, e[1] * dr.y, e[2] * dr.z, e[3] * dr.w);
    }
    __syncthreads();
    if (tid < 64) {
        float s = 0.f;
#pragma unroll
        for (int t = 0; t < 16; t++) s += rm[tid][t];
        Psum[(size_t)blockIdx.x * N_NODES + i0 + tid] = s;
    }
}

// ---------------------------------------------------------------------------
// k_inv: 64 blocks x 32 rows. inv[i] = 1/sum_t Psum[t][i];
// U[i,d]=p[i]*adj[i,d]; Up=inv*U; qpart[blk][d] = sum_{rows} U[i,d].
// ---------------------------------------------------------------------------
__global__ __launch_bounds__(256) void k_inv(
    const float* __restrict__ Psum, const float* __restrict__ adj,
    const float* __restrict__ p,
    float* __restrict__ inv, float* __restrict__ U, float* __restrict__ Up,
    float* __restrict__ qpart)
{
    __shared__ float red[256];
    __shared__ float invL[32];
    __shared__ float uL[32][33];
    const int tid = threadIdx.x;
    const int base = blockIdx.x * 32;
    const int i = tid & 31;
    const int g = tid >> 5;   // 0..7

    float s = 0.f;
#pragma unroll
    for (int t = 0; t < 4; t++)
        s += Psum[(size_t)(g + t * 8) * N_NODES + base + i];
    red[tid] = s;
    __syncthreads();
    if (g == 0) {
        float t = 0.f;
#pragma unroll
        for (int gg = 0; gg < 8; gg++) t += red[gg * 32 + i];
        const float iv = 1.0f / t;
        inv[base + i] = iv;
        invL[i] = iv;
    }
    __syncthreads();

#pragma unroll
    for (int r = 0; r < 4; r++) {
        const int idx = r * 256 + tid;       // 0..1023
        const int row = idx >> 5;
        const float u = p[base + row] * adj[(size_t)base * EMBED + idx];
        uL[row][idx & 31] = u;
        U[(size_t)base * EMBED + idx]  = u;
        Up[(size_t)base * EMBED + idx] = invL[row] * u;
    }
    __syncthreads();
    float qs = 0.f;
#pragma unroll
    for (int r = 0; r < 4; r++) qs += uL[g * 4 + r][i];
    red[tid] = qs;
    __syncthreads();
    if (g == 0) {
        float t = 0.f;
#pragma unroll
        for (int gg = 0; gg < 8; gg++) t += red[gg * 32 + i];
        qpart[blockIdx.x * EMBED + i] = t;
    }
}

// ---------------------------------------------------------------------------
// k_v: Vp[chunk][n][d] partial of V[n,d] = sum_m Ehat[m,n] * Vin[m,d]
// (Vin already has inv folded in).  grid (16 n-tiles x 128, 32 m-chunks x 64).
// ---------------------------------------------------------------------------
__global__ __launch_bounds__(256) void k_v(
    const float* __restrict__ Ehat, const float* __restrict__ Vin,
    float* __restrict__ Vp)
{
    __shared__ float Us[64 * 32];
    const int tid = threadIdx.x;
    const int n  = blockIdx.x * 128 + (tid & 127);
    const int dh = (tid >> 7) * 16;          // 0 or 16
    const int m0 = blockIdx.y * 64;

#pragma unroll
    for (int r = 0; r < 8; r++) {
        const int idx = r * 256 + tid;       // 0..2047
        Us[idx] = Vin[(size_t)m0 * EMBED + idx];
    }
    __syncthreads();

    float4 a0 = {}, a1 = {}, a2 = {}, a3 = {};
    for (int mm = 0; mm < 64; mm++) {
        const float a = Ehat[(size_t)(m0 + mm) * N_NODES + n];
        const float4* u4 = (const float4*)(&Us[mm * 32 + dh]);
        const float4 u0 = u4[0], u1 = u4[1], u2 = u4[2], u3 = u4[3];
        a0.x += a * u0.x; a0.y += a * u0.y; a0.z += a * u0.z; a0.w += a * u0.w;
        a1.x += a * u1.x; a1.y += a * u1.y; a1.z += a * u1.z; a1.w += a * u1.w;
        a2.x += a * u2.x; a2.y += a * u2.y; a2.z += a * u2.z; a2.w += a * u2.w;
        a3.x += a * u3.x; a3.y += a * u3.y; a3.z += a * u3.z; a3.w += a * u3.w;
    }
    float4* out = (float4*)(Vp + (size_t)blockIdx.y * (N_NODES * EMBED)
                               + (size_t)n * EMBED + dh);
    out[0] = a0; out[1] = a1; out[2] = a2; out[3] = a3;
}

// ---------------------------------------------------------------------------
// k_vred: V[idx] = sum over 32 chunks; optionally Vprime = inv[row]*V.
// ---------------------------------------------------------------------------
__global__ __launch_bounds__(256) void k_vred(
    const float* __restrict__ Vp, const float* __restrict__ inv,
    float* __restrict__ V, float* __restrict__ Vprime, int writePrime)
{
    const int idx = blockIdx.x * 256 + threadIdx.x;   // 0..65535
    float s = 0.f;
#pragma unroll
    for (int c = 0; c < 32; c++) s += Vp[(size_t)c * (N_NODES * EMBED) + idx];
    V[idx] = s;
    if (writePrime) Vprime[idx] = inv[idx >> 5] * s;
}

// ---------------------------------------------------------------------------
// k_M: partials of M_k[d,c] = sum_n Vk[n,d] * X'[c,n], all k fused.
// grid (16 c-tiles x 32, 32 n-chunks x 64), 256 threads.
// ---------------------------------------------------------------------------
__global__ __launch_bounds__(256) void k_M(
    const float* __restrict__ XT, const float* __restrict__ V0,
    const float* __restrict__ V1, const float* __restrict__ V2,
    float* __restrict__ Mp)
{
    __shared__ float xs[32][65];
    __shared__ float vs[3][64 * 32];
    const int tid = threadIdx.x;
    const int c0 = blockIdx.x * 32;
    const int n0 = blockIdx.y * 64;
    const int d  = tid >> 3;
    const int cg = (tid & 7) * 4;

#pragma unroll
    for (int r = 0; r < 8; r++) {
        const int idx = r * 256 + tid;        // 0..2047
        xs[idx >> 6][idx & 63] = XT[(size_t)(c0 + (idx >> 6)) * N_NODES + n0 + (idx & 63)];
        vs[0][idx] = V0[(size_t)n0 * EMBED + idx];
        vs[1][idx] = V1[(size_t)n0 * EMBED + idx];
        vs[2][idx] = V2[(size_t)n0 * EMBED + idx];
    }
    __syncthreads();

    float acc[3][4] = {};
#pragma unroll 4
    for (int nn = 0; nn < 64; nn++) {
        const float v0 = vs[0][nn * 32 + d];
        const float v1 = vs[1][nn * 32 + d];
        const float v2 = vs[2][nn * 32 + d];
#pragma unroll
        for (int cc = 0; cc < 4; cc++) {
            const float xv = xs[cg + cc][nn];
            acc[0][cc] += xv * v0;
            acc[1][cc] += xv * v1;
            acc[2][cc] += xv * v2;
        }
    }
#pragma unroll
    for (int k = 0; k < 3; k++) {
        float* dst = Mp + ((size_t)(blockIdx.y * 3 + k) * EMBED + d) * NCOL + c0 + cg;
        *(float4*)dst = make_float4(acc[k][0], acc[k][1], acc[k][2], acc[k][3]);
    }
}

// ---------------------------------------------------------------------------
// k_final: split-d. Block d: load W[d] (12KB) to LDS, reduce Mp over chunks
// (coalesced), compute d-partial of out[b,o], atomicAdd into zeroed d_out.
// Block 0 adds bias (q.bp + pb).
// ---------------------------------------------------------------------------
__global__ __launch_bounds__(256) void k_final(
    const float* __restrict__ Mp, const float* __restrict__ W,
    const float* __restrict__ bp, const float* __restrict__ qpart,
    const float* __restrict__ pb, float* __restrict__ out)
{
    const int d = blockIdx.x;      // 0..31
    const int tid = threadIdx.x;
    __shared__ float wL[3072];     // (k*32+i)*32+o
    __shared__ float mL[3][512];
    __shared__ float qL[32];

#pragma unroll
    for (int r = 0; r < 12; r++) {
        const int idx = r * 256 + tid;           // 0..3071
        const int k = idx >> 10;
        const int rest = idx & 1023;             // i*32+o
        wL[idx] = W[((size_t)(d * 3 + k) << 10) + rest];
    }
#pragma unroll
    for (int r = 0; r < 6; r++) {
        const int e = r * 256 + tid;             // 0..1535
        const int k = e >> 9;
        const int c = e & 511;
        float s = 0.f;
#pragma unroll
        for (int ch = 0; ch < 32; ch++)
            s += Mp[((size_t)(ch * 3 + k) * EMBED + d) * NCOL + c];
        mL[k][c] = s;
    }
    if (d == 0 && tid < 32) {
        float s = 0.f;
#pragma unroll
        for (int blk = 0; blk < 64; blk++) s += qpart[blk * EMBED + tid];
        qL[tid] = s;
    }
    __syncthreads();

#pragma unroll
    for (int r = 0; r < 2; r++) {
        const int pair = r * 256 + tid;          // 0..511 = b*32+o
        const int b = pair >> 5;
        const int o = pair & 31;
        float acc = 0.f;
#pragma unroll
        for (int i = 0; i < 32; i++) {
            const float m0 = mL[0][b * 32 + i];
            const float m1 = mL[1][b * 32 + i];
            const float m2 = mL[2][b * 32 + i];
            const float w0 = wL[(0 * 32 + i) * 32 + o];
            const float w1 = wL[(1 * 32 + i) * 32 + o];
            const float w2 = wL[(2 * 32 + i) * 32 + o];
            acc += m0 * (w0 - w2) + m1 * w1 + 2.f * m2 * w2;
        }
        if (d == 0) {
            float bias = pb[0];
#pragma unroll
            for (int dd = 0; dd < 32; dd++) bias += qL[dd] * bp[dd * OUTC + o];
            acc += bias;
        }
        atomicAdd(&out[pair], acc);
    }
}

// ---------------------------------------------------------------------------
extern "C" void kernel_launch(void* const* d_in, const int* in_sizes, int n_in,
                              void* d_out, int out_size, void* d_ws, size_t ws_size,
                              hipStream_t stream)
{
    const float* x     = (const float*)d_in[0];
    const float* adj   = (const float*)d_in[1];
    const float* gamma = (const float*)d_in[2];
    const float* Wp    = (const float*)d_in[3];
    const float* bp    = (const float*)d_in[4];
    const float* pw    = (const float*)d_in[5];
    const float* pb    = (const float*)d_in[6];
    const float* drop  = (const float*)d_in[7];
    float* out = (float*)d_out;

    float* ws = (float*)d_ws;
    float* Ehat  = ws;                                        // 4,194,304
    float* Vp    = Ehat + (size_t)N_NODES * N_NODES;          // 2,097,152 (aliased Mp)
    float* Mp    = Vp;
    float* Psum  = Vp   + (size_t)32 * N_NODES * EMBED;       // 65,536
    float* inv   = Psum + (size_t)32 * N_NODES;               // 2048
    float* U     = inv  + N_NODES;                            // 65,536
    float* Up    = U    + (size_t)N_NODES * EMBED;            // 65,536
    float* V1    = Up   + (size_t)N_NODES * EMBED;            // 65,536
    float* V1p   = V1   + (size_t)N_NODES * EMBED;            // 65,536
    float* V2    = V1p  + (size_t)N_NODES * EMBED;            // 65,536
    float* qpart = V2   + (size_t)N_NODES * EMBED;            // 2048

    hipMemsetAsync(out, 0, (size_t)B_BATCH * OUTC * sizeof(float), stream);

    k_gram<<<dim3(32, 32), 256, 0, stream>>>(adj, gamma, drop, Ehat, Psum);
    k_inv<<<64, 256, 0, stream>>>(Psum, adj, pw, inv, U, Up, qpart);

    dim3 gv(16, 32);
    k_v<<<gv, 256, 0, stream>>>(Ehat, Up, Vp);
    k_vred<<<256, 256, 0, stream>>>(Vp, inv, V1, V1p, 1);
    k_v<<<gv, 256, 0, stream>>>(Ehat, V1p, Vp);
    k_vred<<<256, 256, 0, stream>>>(Vp, inv, V2, V2, 0);

    k_M<<<dim3(16, 32), 256, 0, stream>>>(x, U, V1, V2, Mp);
    k_final<<<32, 256, 0, stream>>>(Mp, Wp, bp, qpart, pb, out);
}